// Round 6
// baseline (1380.319 us; speedup 1.0000x reference)
//
#include <hip/hip_runtime.h>

typedef short short8 __attribute__((ext_vector_type(8)));
typedef float f32x4 __attribute__((ext_vector_type(4)));

#define N_NODES 100000
#define N_EDGES 1600000
#define D_IN 256
#define D_OUT 128

#define BROWS 64
#define NBUCK 1563           // ceil(100000/64)
#define NGRP 8
#define NCELL (NBUCK * NGRP) // 12504

// ws layout (bytes); total 39,316,480 <= 39.67MB proven in R1.
#define OFF_H     0UL          // bf16 h (pair-packed): 25,600,000
#define OFF_WP    25600000UL   // packed W: 65,536
#define OFF_BCNT  25665536UL   // int[NCELL*16] 64B-padded counters/cursors: 800,768
#define OFF_BOFF  26466304UL   // int[NCELL+1]: 50,176
#define OFF_PEV   26516480UL   // uint2[1.6M]: 12,800,000

__device__ __forceinline__ unsigned short f2bf(float f) {
    unsigned int u = __builtin_bit_cast(unsigned int, f);
    u += 0x7fffu + ((u >> 16) & 1u);   // RNE
    return (unsigned short)(u >> 16);
}

// Pack W [256][128] fp32 -> bf16 MFMA B-fragments.
__global__ void wpack_k(const float* __restrict__ W, unsigned short* __restrict__ wp) {
    int t = blockIdx.x * 256 + threadIdx.x;
    if (t >= 4096) return;
    int ks = t >> 9, nt = (t >> 6) & 7, lane = t & 63;
    int g = lane >> 4, n = nt * 16 + (lane & 15);
    int k0 = ks * 32 + g * 8;
#pragma unroll
    for (int e = 0; e < 8; ++e)
        wp[t * 8 + e] = f2bf(W[(size_t)(k0 + e) * D_OUT + n]);
}

// h = bf16( x @ W + b ). h stored PAIR-PACKED: u32 word (row,slot) holds
// col=slot in low 16 bits, col=slot+64 in high 16 bits (slot 0..63).
__global__ __launch_bounds__(256) void gemm_k(const float* __restrict__ x,
                                              const short8* __restrict__ wq,
                                              const float* __restrict__ b,
                                              unsigned short* __restrict__ h) {
    int wave = threadIdx.x >> 6, lane = threadIdx.x & 63;
    int tile = blockIdx.x * 4 + wave;
    if (tile * 16 >= N_NODES) return;
    int row0 = tile * 16;
    int r = lane & 15, g = lane >> 4;

    f32x4 acc[8];
#pragma unroll
    for (int nt = 0; nt < 8; ++nt)
#pragma unroll
        for (int j = 0; j < 4; ++j) acc[nt][j] = 0.f;

    float bv[8];
#pragma unroll
    for (int nt = 0; nt < 8; ++nt) bv[nt] = b[nt * 16 + r];

    const float4* xp = (const float4*)(x + (size_t)(row0 + r) * D_IN);
#pragma unroll
    for (int ks = 0; ks < 8; ++ks) {
        float4 u0 = xp[ks * 8 + g * 2];
        float4 u1 = xp[ks * 8 + g * 2 + 1];
        short8 af;
        af[0] = (short)f2bf(u0.x); af[1] = (short)f2bf(u0.y);
        af[2] = (short)f2bf(u0.z); af[3] = (short)f2bf(u0.w);
        af[4] = (short)f2bf(u1.x); af[5] = (short)f2bf(u1.y);
        af[6] = (short)f2bf(u1.z); af[7] = (short)f2bf(u1.w);
#pragma unroll
        for (int nt = 0; nt < 8; ++nt) {
            short8 bf = wq[(ks * 8 + nt) * 64 + lane];
            acc[nt] = __builtin_amdgcn_mfma_f32_16x16x32_bf16(af, bf, acc[nt], 0, 0, 0);
        }
    }
    // col c = nt*16+r -> u16 index row*128 + ((nt&3)*16+r)*2 + (nt>>2)
#pragma unroll
    for (int nt = 0; nt < 8; ++nt)
#pragma unroll
        for (int j = 0; j < 4; ++j) {
            float v = acc[nt][j] + bv[nt];
            h[(size_t)(row0 + g * 4 + j) * D_OUT + ((nt & 3) * 16 + r) * 2 + (nt >> 2)] = f2bf(v);
        }
}

// Per-(bucket,group) histogram; group = blockIdx&7 (~XCD under round-robin).
__global__ void bcount_k(const int4* __restrict__ er4, int* __restrict__ bcnt) {
    int t = blockIdx.x * 256 + threadIdx.x;
    int g = blockIdx.x & 7;
    if (t >= N_EDGES / 4) return;
    int4 r = er4[t];
    atomicAdd(&bcnt[((r.x >> 6) * NGRP + g) * 16], 1);
    atomicAdd(&bcnt[((r.y >> 6) * NGRP + g) * 16], 1);
    atomicAdd(&bcnt[((r.z >> 6) * NGRP + g) * 16], 1);
    atomicAdd(&bcnt[((r.w >> 6) * NGRP + g) * 16], 1);
}

// Single-block exclusive scan over NCELL padded counters (13 cells/thread).
// Writes dense boffs AND re-initializes bcnt slots as running cursors.
__global__ __launch_bounds__(1024) void bscan_k(int* __restrict__ bcnt, int* __restrict__ boffs) {
    __shared__ int s[1024];
    int t = threadIdx.x;
    int c0 = t * 13;
    int loc[13];
    int run = 0;
#pragma unroll
    for (int j = 0; j < 13; ++j) {
        int c = c0 + j;
        int v = (c < NCELL) ? bcnt[c * 16] : 0;
        run += v;
        loc[j] = run;   // local inclusive
    }
    s[t] = run;
    __syncthreads();
    for (int off = 1; off < 1024; off <<= 1) {
        int tmp = (t >= off) ? s[t - off] : 0;
        __syncthreads();
        s[t] += tmp;
        __syncthreads();
    }
    int pre = s[t] - run;   // exclusive prefix of this thread's chunk
#pragma unroll
    for (int j = 0; j < 13; ++j) {
        int c = c0 + j;
        int excl = pre + (j ? loc[j - 1] : 0);
        if (c < NCELL) {
            boffs[c] = excl;
            bcnt[c * 16] = excl;   // cursor init
        } else if (c == NCELL) {
            boffs[c] = excl;       // == N_EDGES
        }
    }
}

// Bin edges into (bucket,group) cells. Same-group writers share an XCD ->
// cursor-adjacent 8B stores merge in that XCD's L2 -> dense writeback.
__global__ void bin_k(const int4* __restrict__ er4, const int4* __restrict__ ec4,
                      const float4* __restrict__ ev4,
                      int* __restrict__ bcur, uint2* __restrict__ bpev) {
    int t = blockIdx.x * 256 + threadIdx.x;
    int g = blockIdx.x & 7;
    if (t >= N_EDGES / 4) return;
    int4 r = er4[t];
    int4 c = ec4[t];
    float4 v = ev4[t];
    int rows[4] = {r.x, r.y, r.z, r.w};
    int cols[4] = {c.x, c.y, c.z, c.w};
    float vals[4] = {v.x, v.y, v.z, v.w};
    int pos[4];
#pragma unroll
    for (int i = 0; i < 4; ++i)
        pos[i] = atomicAdd(&bcur[((rows[i] >> 6) * NGRP + g) * 16], 1);
#pragma unroll
    for (int i = 0; i < 4; ++i) {
        uint2 p;
        p.x = (unsigned int)cols[i] | ((unsigned int)(rows[i] & (BROWS - 1)) << 17);
        p.y = __builtin_bit_cast(unsigned int, vals[i]);
        bpev[pos[i]] = p;
    }
}

// One block per bucket: 64x128 f32 LDS tile; bucket's 8 cells are contiguous
// -> one contiguous segment. 8-deep unrolled gather; LDS f32 atomics (2-way
// bank alias = free, thanks to pair-packed h); ReLU + dense coalesced store.
__global__ __launch_bounds__(256) void agg_k(const unsigned int* __restrict__ h32,
                                             const int* __restrict__ boffs,
                                             const uint2* __restrict__ bpev,
                                             float* __restrict__ out) {
    __shared__ float tile[BROWS * 128];  // 32 KB
    for (int i = threadIdx.x; i < BROWS * 128 / 4; i += 256) {
        float4 z = {0.f, 0.f, 0.f, 0.f};
        reinterpret_cast<float4*>(tile)[i] = z;
    }
    __syncthreads();

    int b = blockIdx.x;
    int s = boffs[b * NGRP], e = boffs[b * NGRP + NGRP];
    int wave = threadIdx.x >> 6, lane = threadIdx.x & 63;

    for (int base = s + wave * 8; base < e; base += 32) {
        uint2 p[8];
#pragma unroll
        for (int j = 0; j < 8; ++j) {
            int idx = base + j;
            if (idx < e) p[j] = bpev[idx];
            else { p[j].x = 0u; p[j].y = 0u; }   // val=0 -> no-op
        }
        unsigned int hv[8];
#pragma unroll
        for (int j = 0; j < 8; ++j)
            hv[j] = h32[(size_t)(p[j].x & 0x1FFFFu) * 64 + lane];
#pragma unroll
        for (int j = 0; j < 8; ++j) {
            float v = __builtin_bit_cast(float, p[j].y);
            int rl = (int)(p[j].x >> 17);
            float lo = __builtin_bit_cast(float, hv[j] << 16);          // col = lane
            float hi = __builtin_bit_cast(float, hv[j] & 0xffff0000u);  // col = lane+64
            atomicAdd(&tile[rl * 128 + lane], v * lo);
            atomicAdd(&tile[rl * 128 + 64 + lane], v * hi);
        }
    }
    __syncthreads();

    int row0 = b * BROWS;
    for (int i = threadIdx.x; i < BROWS * 32; i += 256) {
        int r = i >> 5, c4 = i & 31;
        int row = row0 + r;
        if (row < N_NODES) {
            float4 t4 = reinterpret_cast<float4*>(tile)[i];
            t4.x = fmaxf(t4.x, 0.f);
            t4.y = fmaxf(t4.y, 0.f);
            t4.z = fmaxf(t4.z, 0.f);
            t4.w = fmaxf(t4.w, 0.f);
            reinterpret_cast<float4*>(out + (size_t)row * 128)[c4] = t4;
        }
    }
}

extern "C" void kernel_launch(void* const* d_in, const int* in_sizes, int n_in,
                              void* d_out, int out_size, void* d_ws, size_t ws_size,
                              hipStream_t stream) {
    const float* x = (const float*)d_in[0];
    const float* W = (const float*)d_in[1];
    const float* b = (const float*)d_in[2];
    const int* er = (const int*)d_in[3];
    const int* ec = (const int*)d_in[4];
    const float* ev = (const float*)d_in[5];
    float* out = (float*)d_out;
    char* ws = (char*)d_ws;

    unsigned short* h = (unsigned short*)(ws + OFF_H);
    unsigned short* wp = (unsigned short*)(ws + OFF_WP);
    int* bcnt = (int*)(ws + OFF_BCNT);
    int* boffs = (int*)(ws + OFF_BOFF);
    uint2* bpev = (uint2*)(ws + OFF_PEV);

    hipMemsetAsync(bcnt, 0, 800768, stream);

    wpack_k<<<16, 256, 0, stream>>>(W, wp);
    gemm_k<<<1563, 256, 0, stream>>>(x, (const short8*)wp, b, h);
    bcount_k<<<(N_EDGES / 4 + 255) / 256, 256, 0, stream>>>((const int4*)er, bcnt);
    bscan_k<<<1, 1024, 0, stream>>>(bcnt, boffs);
    bin_k<<<(N_EDGES / 4 + 255) / 256, 256, 0, stream>>>((const int4*)er, (const int4*)ec,
                                                         (const float4*)ev, bcnt, bpev);
    agg_k<<<NBUCK, 256, 0, stream>>>((const unsigned int*)h, boffs, bpev, out);
}

// Round 7
// 403.591 us; speedup vs baseline: 3.4201x; 3.4201x over previous
//
#include <hip/hip_runtime.h>

typedef short short8 __attribute__((ext_vector_type(8)));
typedef float f32x4 __attribute__((ext_vector_type(4)));

#define N_NODES 100000
#define N_EDGES 1600000
#define D_IN 256
#define D_OUT 128

#define BROWS 16
#define NBUCK 6250           // 100000/16 exact
#define NGRP 8
#define NCELL (NBUCK * NGRP) // 50000
#define CSTR 4               // ints per padded cell (16B)

// ws layout (bytes); total 39,465,552 (<= R1's proven 39.67MB)
#define OFF_H     0UL          // bf16 h (pair-packed): 25,600,000
#define OFF_WP    25600000UL   // packed W: 65,536
#define OFF_BCNT  25665536UL   // int[NCELL*CSTR]: 800,000
#define OFF_BOFF  26465536UL   // int[NCELL+1]: 200,004 (+pad)
#define OFF_PEV   26665552UL   // uint2[1.6M]: 12,800,000

__device__ __forceinline__ unsigned short f2bf(float f) {
    unsigned int u = __builtin_bit_cast(unsigned int, f);
    u += 0x7fffu + ((u >> 16) & 1u);   // RNE
    return (unsigned short)(u >> 16);
}

// Pack W [256][128] fp32 -> bf16 MFMA B-fragments.
__global__ void wpack_k(const float* __restrict__ W, unsigned short* __restrict__ wp) {
    int t = blockIdx.x * 256 + threadIdx.x;
    if (t >= 4096) return;
    int ks = t >> 9, nt = (t >> 6) & 7, lane = t & 63;
    int g = lane >> 4, n = nt * 16 + (lane & 15);
    int k0 = ks * 32 + g * 8;
#pragma unroll
    for (int e = 0; e < 8; ++e)
        wp[t * 8 + e] = f2bf(W[(size_t)(k0 + e) * D_OUT + n]);
}

// h = bf16( x @ W + b ). h stored PAIR-PACKED: u32 word (row,slot) holds
// col=slot in low 16 bits, col=slot+64 in high 16 bits (slot 0..63).
__global__ __launch_bounds__(256) void gemm_k(const float* __restrict__ x,
                                              const short8* __restrict__ wq,
                                              const float* __restrict__ b,
                                              unsigned short* __restrict__ h) {
    int wave = threadIdx.x >> 6, lane = threadIdx.x & 63;
    int tile = blockIdx.x * 4 + wave;
    if (tile * 16 >= N_NODES) return;
    int row0 = tile * 16;
    int r = lane & 15, g = lane >> 4;

    f32x4 acc[8];
#pragma unroll
    for (int nt = 0; nt < 8; ++nt)
#pragma unroll
        for (int j = 0; j < 4; ++j) acc[nt][j] = 0.f;

    float bv[8];
#pragma unroll
    for (int nt = 0; nt < 8; ++nt) bv[nt] = b[nt * 16 + r];

    const float4* xp = (const float4*)(x + (size_t)(row0 + r) * D_IN);
#pragma unroll
    for (int ks = 0; ks < 8; ++ks) {
        float4 u0 = xp[ks * 8 + g * 2];
        float4 u1 = xp[ks * 8 + g * 2 + 1];
        short8 af;
        af[0] = (short)f2bf(u0.x); af[1] = (short)f2bf(u0.y);
        af[2] = (short)f2bf(u0.z); af[3] = (short)f2bf(u0.w);
        af[4] = (short)f2bf(u1.x); af[5] = (short)f2bf(u1.y);
        af[6] = (short)f2bf(u1.z); af[7] = (short)f2bf(u1.w);
#pragma unroll
        for (int nt = 0; nt < 8; ++nt) {
            short8 bf = wq[(ks * 8 + nt) * 64 + lane];
            acc[nt] = __builtin_amdgcn_mfma_f32_16x16x32_bf16(af, bf, acc[nt], 0, 0, 0);
        }
    }
#pragma unroll
    for (int nt = 0; nt < 8; ++nt)
#pragma unroll
        for (int j = 0; j < 4; ++j) {
            float v = acc[nt][j] + bv[nt];
            h[(size_t)(row0 + g * 4 + j) * D_OUT + ((nt & 3) * 16 + r) * 2 + (nt >> 2)] = f2bf(v);
        }
}

// Per-(16-row bucket, XCD group) histogram on 16B-padded counters.
__global__ void bcount_k(const int4* __restrict__ er4, int* __restrict__ bcnt) {
    int t = blockIdx.x * 256 + threadIdx.x;
    int g = blockIdx.x & 7;
    if (t >= N_EDGES / 4) return;
    int4 r = er4[t];
    atomicAdd(&bcnt[((r.x >> 4) * NGRP + g) * CSTR], 1);
    atomicAdd(&bcnt[((r.y >> 4) * NGRP + g) * CSTR], 1);
    atomicAdd(&bcnt[((r.z >> 4) * NGRP + g) * CSTR], 1);
    atomicAdd(&bcnt[((r.w >> 4) * NGRP + g) * CSTR], 1);
}

// Single-block exclusive scan over NCELL padded counters (49 cells/thread).
// Writes dense boffs AND re-initializes bcnt slots as running cursors.
#define CH 49
__global__ __launch_bounds__(1024) void bscan_k(int* __restrict__ bcnt, int* __restrict__ boffs) {
    __shared__ int s[1024];
    int t = threadIdx.x;
    int c0 = t * CH;
    int loc[CH];
    int run = 0;
#pragma unroll
    for (int j = 0; j < CH; ++j) {
        int c = c0 + j;
        int v = (c < NCELL) ? bcnt[c * CSTR] : 0;
        run += v;
        loc[j] = run;   // local inclusive
    }
    s[t] = run;
    __syncthreads();
    for (int off = 1; off < 1024; off <<= 1) {
        int tmp = (t >= off) ? s[t - off] : 0;
        __syncthreads();
        s[t] += tmp;
        __syncthreads();
    }
    int pre = s[t] - run;   // exclusive prefix of this thread's chunk
#pragma unroll
    for (int j = 0; j < CH; ++j) {
        int c = c0 + j;
        int excl = pre + (j ? loc[j - 1] : 0);
        if (c < NCELL) {
            boffs[c] = excl;
            bcnt[c * CSTR] = excl;   // cursor init
        } else if (c == NCELL) {
            boffs[c] = excl;         // == N_EDGES
        }
    }
}

// Bin edges into (bucket,group) cells; same-group writers share an XCD ->
// cursor-adjacent 8B stores merge into dense lines in that XCD's L2.
__global__ void bin_k(const int4* __restrict__ er4, const int4* __restrict__ ec4,
                      const float4* __restrict__ ev4,
                      int* __restrict__ bcur, uint2* __restrict__ bpev) {
    int t = blockIdx.x * 256 + threadIdx.x;
    int g = blockIdx.x & 7;
    if (t >= N_EDGES / 4) return;
    int4 r = er4[t];
    int4 c = ec4[t];
    float4 v = ev4[t];
    int rows[4] = {r.x, r.y, r.z, r.w};
    int cols[4] = {c.x, c.y, c.z, c.w};
    float vals[4] = {v.x, v.y, v.z, v.w};
    int pos[4];
#pragma unroll
    for (int i = 0; i < 4; ++i)
        pos[i] = atomicAdd(&bcur[((rows[i] >> 4) * NGRP + g) * CSTR], 1);
#pragma unroll
    for (int i = 0; i < 4; ++i) {
        uint2 p;
        p.x = (unsigned int)cols[i] | ((unsigned int)(rows[i] & (BROWS - 1)) << 17);
        p.y = __builtin_bit_cast(unsigned int, vals[i]);
        bpev[pos[i]] = p;
    }
}

// One WAVE per 16-row bucket: private 16x128 f32 LDS tile, NO atomics
// (same-wave DS ops are in-order). 8-deep unrolled gather for MLP.
// 2 waves/block -> 16KB LDS -> 10 blocks/CU = 20 waves/CU.
__global__ __launch_bounds__(128) void agg_k(const unsigned int* __restrict__ h32,
                                             const int* __restrict__ boffs,
                                             const uint2* __restrict__ bpev,
                                             float* __restrict__ out) {
    __shared__ float tile[2][BROWS * 128];  // 2 x 8KB, one per wave
    int w = threadIdx.x >> 6, lane = threadIdx.x & 63;
    float* T = tile[w];
    int b = blockIdx.x * 2 + w;   // bucket, < 6250 always

    for (int i = lane; i < BROWS * 128 / 4; i += 64) {
        float4 z = {0.f, 0.f, 0.f, 0.f};
        reinterpret_cast<float4*>(T)[i] = z;
    }
    // no barrier: tile half is wave-private, DS in-order within wave

    int s = boffs[b * NGRP], e = boffs[b * NGRP + NGRP];
    for (int base = s; base < e; base += 8) {
        uint2 p[8];
#pragma unroll
        for (int j = 0; j < 8; ++j) {
            int idx = base + j;
            if (idx < e) p[j] = bpev[idx];
            else { p[j].x = 0u; p[j].y = 0u; }   // val=0 -> no-op
        }
        unsigned int hv[8];
#pragma unroll
        for (int j = 0; j < 8; ++j)
            hv[j] = h32[(size_t)(p[j].x & 0x1FFFFu) * 64 + lane];
#pragma unroll
        for (int j = 0; j < 8; ++j) {
            float v = __builtin_bit_cast(float, p[j].y);
            int rl = (int)(p[j].x >> 17);
            float lo = __builtin_bit_cast(float, hv[j] << 16);          // col = lane
            float hi = __builtin_bit_cast(float, hv[j] & 0xffff0000u);  // col = lane+64
            int idx = rl * 128 + lane;
            float t0 = T[idx], t1 = T[idx + 64];
            T[idx] = fmaf(v, lo, t0);
            T[idx + 64] = fmaf(v, hi, t1);
        }
    }

    int row0 = b * BROWS;
    const float2* T2 = reinterpret_cast<const float2*>(T);
#pragma unroll
    for (int r = 0; r < BROWS; ++r) {
        float2 t2 = T2[r * 64 + lane];
        t2.x = fmaxf(t2.x, 0.f);
        t2.y = fmaxf(t2.y, 0.f);
        reinterpret_cast<float2*>(out + (size_t)(row0 + r) * 128)[lane] = t2;
    }
}

extern "C" void kernel_launch(void* const* d_in, const int* in_sizes, int n_in,
                              void* d_out, int out_size, void* d_ws, size_t ws_size,
                              hipStream_t stream) {
    const float* x = (const float*)d_in[0];
    const float* W = (const float*)d_in[1];
    const float* b = (const float*)d_in[2];
    const int* er = (const int*)d_in[3];
    const int* ec = (const int*)d_in[4];
    const float* ev = (const float*)d_in[5];
    float* out = (float*)d_out;
    char* ws = (char*)d_ws;

    unsigned short* h = (unsigned short*)(ws + OFF_H);
    unsigned short* wp = (unsigned short*)(ws + OFF_WP);
    int* bcnt = (int*)(ws + OFF_BCNT);
    int* boffs = (int*)(ws + OFF_BOFF);
    uint2* bpev = (uint2*)(ws + OFF_PEV);

    hipMemsetAsync(bcnt, 0, (size_t)NCELL * CSTR * 4, stream);

    wpack_k<<<16, 256, 0, stream>>>(W, wp);
    gemm_k<<<1563, 256, 0, stream>>>(x, (const short8*)wp, b, h);
    bcount_k<<<(N_EDGES / 4 + 255) / 256, 256, 0, stream>>>((const int4*)er, bcnt);
    bscan_k<<<1, 1024, 0, stream>>>(bcnt, boffs);
    bin_k<<<(N_EDGES / 4 + 255) / 256, 256, 0, stream>>>((const int4*)er, (const int4*)ec,
                                                         (const float4*)ev, bcnt, bpev);
    agg_k<<<NBUCK / 2, 128, 0, stream>>>((const unsigned int*)h, boffs, bpev, out);
}

// Round 8
// 280.663 us; speedup vs baseline: 4.9181x; 1.4380x over previous
//
#include <hip/hip_runtime.h>

typedef short short8 __attribute__((ext_vector_type(8)));
typedef float f32x4 __attribute__((ext_vector_type(4)));

#define N_NODES 100000
#define N_EDGES 1600000
#define D_IN 256
#define D_OUT 128

#define BROWS 16
#define NBUCK 6250           // 100000/16 exact
#define NGRP 8
#define NCELL (NBUCK * NGRP) // 50000
#define CSTR 4               // ints per padded cell (16B)
#define NSB 49               // scan blocks: 49*1024 = 50176 >= NCELL

// ws layout (bytes); total ~39.47MB (<= R1's proven 39.67MB)
#define OFF_H     0UL          // bf16 h (pair-packed): 25,600,000
#define OFF_WP    25600000UL   // packed W: 65,536
#define OFF_BCNT  25665536UL   // int[NCELL*CSTR]: 800,000
#define OFF_BOFF  26465536UL   // int[NCELL+1]: 200,004 (+pad to 200,016)
#define OFF_BS    26665552UL   // int[64] scan block sums: 256
#define OFF_PEV   26665808UL   // uint2[1.6M]: 12,800,000

__device__ __forceinline__ unsigned short f2bf(float f) {
    unsigned int u = __builtin_bit_cast(unsigned int, f);
    u += 0x7fffu + ((u >> 16) & 1u);   // RNE
    return (unsigned short)(u >> 16);
}

// Pack W [256][128] fp32 -> bf16 MFMA B-fragments.
__global__ void wpack_k(const float* __restrict__ W, unsigned short* __restrict__ wp) {
    int t = blockIdx.x * 256 + threadIdx.x;
    if (t >= 4096) return;
    int ks = t >> 9, nt = (t >> 6) & 7, lane = t & 63;
    int g = lane >> 4, n = nt * 16 + (lane & 15);
    int k0 = ks * 32 + g * 8;
#pragma unroll
    for (int e = 0; e < 8; ++e)
        wp[t * 8 + e] = f2bf(W[(size_t)(k0 + e) * D_OUT + n]);
}

// h = bf16( x @ W + b ). h stored PAIR-PACKED: u32 word (row,slot) holds
// col=slot in low 16 bits, col=slot+64 in high 16 bits (slot 0..63).
__global__ __launch_bounds__(256) void gemm_k(const float* __restrict__ x,
                                              const short8* __restrict__ wq,
                                              const float* __restrict__ b,
                                              unsigned short* __restrict__ h) {
    int wave = threadIdx.x >> 6, lane = threadIdx.x & 63;
    int tile = blockIdx.x * 4 + wave;
    if (tile * 16 >= N_NODES) return;
    int row0 = tile * 16;
    int r = lane & 15, g = lane >> 4;

    f32x4 acc[8];
#pragma unroll
    for (int nt = 0; nt < 8; ++nt)
#pragma unroll
        for (int j = 0; j < 4; ++j) acc[nt][j] = 0.f;

    float bv[8];
#pragma unroll
    for (int nt = 0; nt < 8; ++nt) bv[nt] = b[nt * 16 + r];

    const float4* xp = (const float4*)(x + (size_t)(row0 + r) * D_IN);
#pragma unroll
    for (int ks = 0; ks < 8; ++ks) {
        float4 u0 = xp[ks * 8 + g * 2];
        float4 u1 = xp[ks * 8 + g * 2 + 1];
        short8 af;
        af[0] = (short)f2bf(u0.x); af[1] = (short)f2bf(u0.y);
        af[2] = (short)f2bf(u0.z); af[3] = (short)f2bf(u0.w);
        af[4] = (short)f2bf(u1.x); af[5] = (short)f2bf(u1.y);
        af[6] = (short)f2bf(u1.z); af[7] = (short)f2bf(u1.w);
#pragma unroll
        for (int nt = 0; nt < 8; ++nt) {
            short8 bf = wq[(ks * 8 + nt) * 64 + lane];
            acc[nt] = __builtin_amdgcn_mfma_f32_16x16x32_bf16(af, bf, acc[nt], 0, 0, 0);
        }
    }
#pragma unroll
    for (int nt = 0; nt < 8; ++nt)
#pragma unroll
        for (int j = 0; j < 4; ++j) {
            float v = acc[nt][j] + bv[nt];
            h[(size_t)(row0 + g * 4 + j) * D_OUT + ((nt & 3) * 16 + r) * 2 + (nt >> 2)] = f2bf(v);
        }
}

// Per-(16-row bucket, XCD group) histogram on 16B-padded counters.
__global__ void bcount_k(const int4* __restrict__ er4, int* __restrict__ bcnt) {
    int t = blockIdx.x * 256 + threadIdx.x;
    int g = blockIdx.x & 7;
    if (t >= N_EDGES / 4) return;
    int4 r = er4[t];
    atomicAdd(&bcnt[((r.x >> 4) * NGRP + g) * CSTR], 1);
    atomicAdd(&bcnt[((r.y >> 4) * NGRP + g) * CSTR], 1);
    atomicAdd(&bcnt[((r.z >> 4) * NGRP + g) * CSTR], 1);
    atomicAdd(&bcnt[((r.w >> 4) * NGRP + g) * CSTR], 1);
}

// Hierarchical scan over NCELL padded counters (R2-proven structure).
// scan1: per-1024-block inclusive Hillis-Steele -> boffs (inclusive), block sums.
__global__ __launch_bounds__(1024) void scan1_k(const int* __restrict__ bcnt,
                                                int* __restrict__ boffs,
                                                int* __restrict__ bs) {
    __shared__ int s[1024];
    int t = threadIdx.x;
    int c = blockIdx.x * 1024 + t;
    int v = (c < NCELL) ? bcnt[c * CSTR] : 0;
    s[t] = v;
    __syncthreads();
    for (int off = 1; off < 1024; off <<= 1) {
        int tmp = (t >= off) ? s[t - off] : 0;
        __syncthreads();
        s[t] += tmp;
        __syncthreads();
    }
    if (c < NCELL) boffs[c] = s[t];
    if (t == 1023) bs[blockIdx.x] = s[1023];
}

__global__ void scan2_k(int* __restrict__ bs, int nb) {
    if (threadIdx.x == 0) {
        int run = 0;
        for (int bb = 0; bb < nb; ++bb) { int t = bs[bb]; bs[bb] = run; run += t; }
        bs[nb] = run;
    }
}

// inclusive->exclusive + block base; writes final boffs AND cursor-inits bcnt.
__global__ void scan3_k(int* __restrict__ boffs, int* __restrict__ bcnt,
                        const int* __restrict__ bs) {
    int c = blockIdx.x * 256 + threadIdx.x;
    if (c < NCELL) {
        int v = boffs[c] - bcnt[c * CSTR] + bs[c >> 10];
        boffs[c] = v;
        bcnt[c * CSTR] = v;   // cursor init
    }
    if (c == 0) boffs[NCELL] = bs[NSB];   // == N_EDGES
}

// Bin edges into (bucket,group) cells; same-group writers share an XCD ->
// cursor-adjacent 8B stores merge into dense lines in that XCD's L2.
__global__ void bin_k(const int4* __restrict__ er4, const int4* __restrict__ ec4,
                      const float4* __restrict__ ev4,
                      int* __restrict__ bcur, uint2* __restrict__ bpev) {
    int t = blockIdx.x * 256 + threadIdx.x;
    int g = blockIdx.x & 7;
    if (t >= N_EDGES / 4) return;
    int4 r = er4[t];
    int4 c = ec4[t];
    float4 v = ev4[t];
    int rows[4] = {r.x, r.y, r.z, r.w};
    int cols[4] = {c.x, c.y, c.z, c.w};
    float vals[4] = {v.x, v.y, v.z, v.w};
    int pos[4];
#pragma unroll
    for (int i = 0; i < 4; ++i)
        pos[i] = atomicAdd(&bcur[((rows[i] >> 4) * NGRP + g) * CSTR], 1);
#pragma unroll
    for (int i = 0; i < 4; ++i) {
        uint2 p;
        p.x = (unsigned int)cols[i] | ((unsigned int)(rows[i] & (BROWS - 1)) << 17);
        p.y = __builtin_bit_cast(unsigned int, vals[i]);
        bpev[pos[i]] = p;
    }
}

// One WAVE per 16-row bucket: private 16x128 f32 LDS tile, NO atomics
// (same-wave DS ops are in-order). 8-deep unrolled gather for MLP.
__global__ __launch_bounds__(128) void agg_k(const unsigned int* __restrict__ h32,
                                             const int* __restrict__ boffs,
                                             const uint2* __restrict__ bpev,
                                             float* __restrict__ out) {
    __shared__ float tile[2][BROWS * 128];  // 2 x 8KB, one per wave
    int w = threadIdx.x >> 6, lane = threadIdx.x & 63;
    float* T = tile[w];
    int b = blockIdx.x * 2 + w;   // bucket, < 6250 always

    for (int i = lane; i < BROWS * 128 / 4; i += 64) {
        float4 z = {0.f, 0.f, 0.f, 0.f};
        reinterpret_cast<float4*>(T)[i] = z;
    }
    // no barrier: tile half is wave-private, DS in-order within wave

    int s = boffs[b * NGRP], e = boffs[b * NGRP + NGRP];
    for (int base = s; base < e; base += 8) {
        uint2 p[8];
#pragma unroll
        for (int j = 0; j < 8; ++j) {
            int idx = base + j;
            if (idx < e) p[j] = bpev[idx];
            else { p[j].x = 0u; p[j].y = 0u; }   // val=0 -> no-op
        }
        unsigned int hv[8];
#pragma unroll
        for (int j = 0; j < 8; ++j)
            hv[j] = h32[(size_t)(p[j].x & 0x1FFFFu) * 64 + lane];
#pragma unroll
        for (int j = 0; j < 8; ++j) {
            float v = __builtin_bit_cast(float, p[j].y);
            int rl = (int)(p[j].x >> 17);
            float lo = __builtin_bit_cast(float, hv[j] << 16);          // col = lane
            float hi = __builtin_bit_cast(float, hv[j] & 0xffff0000u);  // col = lane+64
            int idx = rl * 128 + lane;
            float t0 = T[idx], t1 = T[idx + 64];
            T[idx] = fmaf(v, lo, t0);
            T[idx + 64] = fmaf(v, hi, t1);
        }
    }

    int row0 = b * BROWS;
    const float2* T2 = reinterpret_cast<const float2*>(T);
#pragma unroll
    for (int r = 0; r < BROWS; ++r) {
        float2 t2 = T2[r * 64 + lane];
        t2.x = fmaxf(t2.x, 0.f);
        t2.y = fmaxf(t2.y, 0.f);
        reinterpret_cast<float2*>(out + (size_t)(row0 + r) * 128)[lane] = t2;
    }
}

extern "C" void kernel_launch(void* const* d_in, const int* in_sizes, int n_in,
                              void* d_out, int out_size, void* d_ws, size_t ws_size,
                              hipStream_t stream) {
    const float* x = (const float*)d_in[0];
    const float* W = (const float*)d_in[1];
    const float* b = (const float*)d_in[2];
    const int* er = (const int*)d_in[3];
    const int* ec = (const int*)d_in[4];
    const float* ev = (const float*)d_in[5];
    float* out = (float*)d_out;
    char* ws = (char*)d_ws;

    unsigned short* h = (unsigned short*)(ws + OFF_H);
    unsigned short* wp = (unsigned short*)(ws + OFF_WP);
    int* bcnt = (int*)(ws + OFF_BCNT);
    int* boffs = (int*)(ws + OFF_BOFF);
    int* bs = (int*)(ws + OFF_BS);
    uint2* bpev = (uint2*)(ws + OFF_PEV);

    hipMemsetAsync(bcnt, 0, (size_t)NCELL * CSTR * 4, stream);

    wpack_k<<<16, 256, 0, stream>>>(W, wp);
    gemm_k<<<1563, 256, 0, stream>>>(x, (const short8*)wp, b, h);
    bcount_k<<<(N_EDGES / 4 + 255) / 256, 256, 0, stream>>>((const int4*)er, bcnt);
    scan1_k<<<NSB, 1024, 0, stream>>>(bcnt, boffs, bs);
    scan2_k<<<1, 64, 0, stream>>>(bs, NSB);
    scan3_k<<<(NCELL + 255) / 256, 256, 0, stream>>>(boffs, bcnt, bs);
    bin_k<<<(N_EDGES / 4 + 255) / 256, 256, 0, stream>>>((const int4*)er, (const int4*)ec,
                                                         (const float4*)ev, bcnt, bpev);
    agg_k<<<NBUCK / 2, 128, 0, stream>>>((const unsigned int*)h, boffs, bpev, out);
}